// Round 1
// baseline (254.033 us; speedup 1.0000x reference)
//
#include <hip/hip_runtime.h>
#include <math.h>

#ifndef M_PI
#define M_PI 3.14159265358979323846
#endif

#define TPB 256

// ---------------------------------------------------------------------------
// Workspace layout (doubles):
//   ws[0..31]   : scalars for L1
//   ws[32..63]  : scalars for L2
//   ws[64..64+B): per-batch contributions
// Per-L scalar layout:
//   0..5 : Sinv_m upper triangle (00,01,02,11,12,22)
//   6..8 : Sinv_s (00,01,11)
//   9    : det_m        10 : det_s        11 : q
//   12..14 : Gff,Gfv,Gvv (wo @ wo.T entries)
//   15 : alpha_br (W last diag entry AND w_tx factor)
//   16 : kf = alpha_br/Tm     17 : kv = alpha_br/(2 Tm^2)    18 : Tm
//   19 : W_aa   20 : g2   21 : sig_a^2
// ---------------------------------------------------------------------------

__device__ double block_sum_d(double v, double* buf) {
    int tid = threadIdx.x;
    buf[tid] = v;
    __syncthreads();
    for (int o = TPB / 2; o > 0; o >>= 1) {
        if (tid < o) buf[tid] += buf[tid + o];
        __syncthreads();
    }
    double r = buf[0];
    __syncthreads();
    return r;
}

__global__ __launch_bounds__(TPB) void precompute_kernel(
    const float* __restrict__ t, const float* __restrict__ t_wait,
    const float* __restrict__ t_SM, const float* __restrict__ t_wait_SM,
    const float* __restrict__ hsig_f, const float* __restrict__ hsig_w,
    const float* __restrict__ hxi_f, const float* __restrict__ hxi_w,
    const float* __restrict__ hxi_v, const float* __restrict__ delta0,
    const float* __restrict__ halpha, const float* __restrict__ hg,
    const float* __restrict__ hW_aa, const float* __restrict__ hsig_a,
    int B, int NT, double* __restrict__ ws)
{
    __shared__ double buf[TPB];
    __shared__ double sh[2];
    int tid = threadIdx.x;

    // mean(t_wait), mean(t_wait_SM)
    double s1 = 0.0, s2 = 0.0;
    for (int i = tid; i < B; i += TPB) {
        s1 += (double)t_wait[i];
        s2 += (double)t_wait_SM[i];
    }
    double tw1 = block_sum_d(s1, buf);
    double tw2 = block_sum_d(s2, buf);
    if (tid == 0) { sh[0] = 3.0 - tw1 / (double)B; sh[1] = 3.0 - tw2 / (double)B; }
    __syncthreads();
    double Tm1 = sh[0], Tm2 = sh[1];

    // Gram moments of rem over tau (row 0 of t / t_SM)
    double a2 = 0, a3 = 0, a4 = 0, b2 = 0, b3 = 0, b4 = 0;
    for (int i = tid; i < NT; i += TPB) {
        double r1 = Tm1 - (double)t[i];    r1 = r1 > 0.0 ? r1 : 0.0;
        double r2 = Tm2 - (double)t_SM[i]; r2 = r2 > 0.0 ? r2 : 0.0;
        double r1s = r1 * r1, r2s = r2 * r2;
        a2 += r1s; a3 += r1s * r1; a4 += r1s * r1s;
        b2 += r2s; b3 += r2s * r2; b4 += r2s * r2s;
    }
    a2 = block_sum_d(a2, buf); a3 = block_sum_d(a3, buf); a4 = block_sum_d(a4, buf);
    b2 = block_sum_d(b2, buf); b3 = block_sum_d(b3, buf); b4 = block_sum_d(b4, buf);
    if (tid != 0) return;

    double sig_f = exp((double)hsig_f[0]);
    double sig_w = exp((double)hsig_w[0]);
    double xi_f  = exp((double)hxi_f[0]);
    double xi_w  = exp((double)hxi_w[0]);
    double xi_v  = exp((double)hxi_v[0]);
    double d0    = (double)delta0[0];
    double alpha = exp((double)halpha[0]);
    double g     = exp((double)hg[0]);
    double W_aa  = exp((double)hW_aa[0]);
    double sig_a = exp((double)hsig_a[0]);
    double g2 = g * g, sig_a2 = sig_a * sig_a;

    for (int L = 0; L < 2; ++L) {
        double sf, xv, ab, Tm, S2, S3, S4;
        if (L == 0) { sf = sig_f; xv = xi_v; ab = alpha; Tm = Tm1; S2 = a2; S3 = a3; S4 = a4; }
        else {
            sf = sqrt(sig_f * sig_f + sig_w * sig_w);
            xv = sqrt(xi_v * xi_v + xi_w * xi_w);
            ab = alpha * W_aa; Tm = Tm2; S2 = b2; S3 = b3; S4 = b4;
        }
        // t_obs = 1
        double xf_ = xi_f / sf, xv_ = xv / sf;
        double t_avg = 0.5, t2_avg = 1.0 / 3.0, C_t = 1.0 / 12.0;
        double ixf2 = 1.0 / (xf_ * xf_), ixv2 = 1.0 / (xv_ * xv_);
        double det_inv = (1.0 + ixf2) * (C_t + ixv2) + t_avg * t_avg * ixf2;

        // _sigma_move (block-diag 3x3) -> inverse + det in closed form
        double pre_m = sf * sf / (det_inv * det_inv);
        double Sff = (C_t + ixv2) * (C_t + ixv2) + C_t * t_avg * t_avg;
        double Sfv = t_avg * (ixf2 * ixv2 - C_t);
        double Svv = (t_avg * ixf2) * (t_avg * ixf2) + C_t * (1.0 + ixf2) * (1.0 + ixf2);
        double m11 = pre_m * Sff, m12 = pre_m * Sfv, m22 = pre_m * Svv;
        double detB = m11 * m22 - m12 * m12;
        double Sm00 = 1.0 / sig_a2, Sm01 = 0.0, Sm02 = 0.0;
        double Sm11 = m22 / detB, Sm12 = -m12 / detB, Sm22 = m11 / detB;
        double det_m = sig_a2 * detB;

        // _sigma_stat (2x2)
        double pre_s = sf * sf;
        double Sffs = pre_s / ((1.0 + ixf2) * (1.0 + ixf2));
        double Sfvs = pre_s * (t_avg / (xf_ * xf_ + 1.0)) / det_inv;
        double Svvs = pre_s * ((t_avg * ixf2) * (t_avg * ixf2) + C_t * (1.0 + ixf2) * (1.0 + ixf2)) / (det_inv * det_inv);
        double det_s = Sffs * Svvs - Sfvs * Sfvs;
        double Ss00 = Svvs / det_s, Ss01 = -Sfvs / det_s, Ss11 = Sffs / det_s;

        // _threshold
        double log_arg = 1.0 + xv_ * xv_ * (C_t + t2_avg / (1.0 + xf_ * xf_));
        double det_ratio = (1.0 / (sf * sf)) * (C_t + 1.0 / (xv_ * xv_) + t2_avg / (1.0 + xf_ * xf_));
        double tq = (log(log_arg) - 2.0 * d0) / det_ratio;
        double q = sqrt(tq > 0.0 ? tq : 0.0);

        // control weights: w_f = kf*rem, w_v = kv*rem^2, w_tv == w_f
        double kf = ab / Tm, kv = ab / (2.0 * Tm * Tm);
        double Gff = kf * kf * S2, Gfv = kf * kv * S3, Gvv = kv * kv * S4;

        double* w = ws + L * 32;
        w[0] = Sm00; w[1] = Sm01; w[2] = Sm02; w[3] = Sm11; w[4] = Sm12; w[5] = Sm22;
        w[6] = Ss00; w[7] = Ss01; w[8] = Ss11;
        w[9] = det_m; w[10] = det_s; w[11] = q;
        w[12] = Gff; w[13] = Gfv; w[14] = Gvv;
        w[15] = ab; w[16] = kf; w[17] = kv; w[18] = Tm;
        w[19] = W_aa; w[20] = g2; w[21] = sig_a2;
    }
}

// Per-batch scalar epilogue (both branches of _get_L + combine), double precision.
__device__ double epilogue(const double* __restrict__ S, int NT,
                           double s2, double R1, double R2,
                           double z0, double z1, double z2, double dtb)
{
    double Sm00 = S[0], Sm01 = S[1], Sm02 = S[2], Sm11 = S[3], Sm12 = S[4], Sm22 = S[5];
    double Ss00 = S[6], Ss01 = S[7], Ss11 = S[8];
    double det_m = S[9], det_s = S[10], q = S[11];
    double Gff = S[12], Gfv = S[13], Gvv = S[14];
    double ab = S[15], kf = S[16], kv = S[17];
    double W_aa = S[19], g2 = S[20], sig_a2 = S[21];

    double cb = dtb / g2;
    double df = kf * R1, dv = kv * R2;     // dot(w_f,resid), dot(w_v,resid)
    double data_quad = 0.5 * cb * s2;

    // ---- move branch (3x3, with_ctrl_v=True) ----
    double Svo0 = Sm02, Svo1 = Sm12, Svv = Sm22;
    double A00 = Sm00 + cb * Gff, A01 = Sm01 + cb * Gfv, A11 = Sm11 + cb * Gvv;
    double detA = A00 * A11 - A01 * A01;
    double i00 = A11 / detA, i01 = -A01 / detA, i11 = A00 / detA;
    double Woz0 = W_aa * z0, Woz1 = z1, Wvz = ab * z2;
    double Jr0 = Woz0 * Sm00 + Woz1 * Sm01 + Wvz * Svo0 + cb * df;
    double Jr1 = Woz0 * Sm01 + Woz1 * Sm11 + Wvz * Svo1 + cb * dv;
    double Jv0 = Svo0 + cb * Gff, Jv1 = Svo1 + cb * Gfv;   // wo @ w_tv = (Gff,Gfv)
    double AiJv0 = i00 * Jv0 + i01 * Jv1, AiJv1 = i01 * Jv0 + i11 * Jv1;
    double AiJr0 = i00 * Jr0 + i01 * Jr1, AiJr1 = i01 * Jr0 + i11 * Jr1;
    double Jm = Svv * Wvz + Woz0 * Svo0 + Woz1 * Svo1 + cb * df
              - (Jr0 * AiJv0 + Jr1 * AiJv1);
    double km = Svv + cb * Gff - (Jv0 * AiJv0 + Jv1 * AiJv1);  // sum(w_tv^2)=Gff/... scaled: cb*Gff
    double y0 = W_aa * z0, y1 = z1, y2 = ab * z2;  // W z
    double zq = y0 * y0 * Sm00 + y1 * y1 * Sm11 + y2 * y2 * Sm22
              + 2.0 * (y0 * y1 * Sm01 + y0 * y2 * Sm02 + y1 * y2 * Sm12);
    double Zm = 0.5 * zq + data_quad - 0.5 * (Jr0 * AiJr0 + Jr1 * AiJr1) - 0.5 * Jm * Jm / km;

    // ---- stat branch (2x2, with_ctrl_v=False, zz = z[1:], wo = w_f) ----
    double As = Ss00 + cb * Gff;           // 1x1 A
    double Wozs = z1, Wvzs = ab * z2;
    double Jrs = Wozs * Ss00 + Wvzs * Ss01 + cb * df;
    double Jvs = Ss01;
    double Js = Ss11 * Wvzs + Wozs * Ss01 - Jrs * Jvs / As;
    double ks = Ss11 - Jvs * Jvs / As;
    double ys1 = ab * z2;
    double zqs = z1 * z1 * Ss00 + 2.0 * z1 * ys1 * Ss01 + ys1 * ys1 * Ss11;
    double Zs = 0.5 * zqs + data_quad - 0.5 * Jrs * Jrs / As - 0.5 * Js * Js / ks;

    // ---- combine ----
    double pre_m = km * detA * det_m * sig_a2;
    double pre_s = ks * As * det_s;
    double sm = sqrt(2.0 * km), ss = sqrt(2.0 * ks);
    double em = 1.0 + 0.5 * erf((Jm - km * q) / sm) - 0.5 * erf((Jm + km * q) / sm);
    double es = 0.5 * erf((Js + ks * q) / ss) - 0.5 * erf((Js - ks * q) / ss);
    double Lm = exp(-Zm) * em / sqrt(pre_m);
    double Ls = exp(-Zs) * es / sqrt(pre_s);
    return (double)NT * log(2.0 * M_PI * g2 / dtb) - log(Lm + Ls);
}

__global__ __launch_bounds__(TPB) void batch_kernel(
    const float* __restrict__ u_t, const float* __restrict__ x_t,
    const float* __restrict__ z, const float* __restrict__ t,
    const float* __restrict__ u_SM, const float* __restrict__ x_SM,
    const float* __restrict__ z_SM, const float* __restrict__ t_SM,
    int NT, const double* __restrict__ ws, double* __restrict__ contrib)
{
    int b = blockIdx.x, tid = threadIdx.x;
    float ab1 = (float)ws[15], Tm1f = (float)ws[18];
    float ab2 = (float)ws[32 + 15], Tm2f = (float)ws[32 + 18];
    size_t off = (size_t)b * (size_t)NT;
    const float4* U1 = (const float4*)(u_t + off);
    const float4* X1 = (const float4*)(x_t + off);
    const float4* U2 = (const float4*)(u_SM + off);
    const float4* X2 = (const float4*)(x_SM + off);
    const float4* T1 = (const float4*)t;      // row 0 (tau)
    const float4* T2 = (const float4*)t_SM;   // row 0 (tau_SM)
    int n4 = NT >> 2;

    float s2a = 0, r1a = 0, r2a = 0, s2b = 0, r1b = 0, r2b = 0;
    for (int i = tid; i < n4; i += TPB) {
        float4 u = U1[i], x = X1[i], ta = T1[i];
        float4 uu = U2[i], xx = X2[i], tb = T2[i];
        float uc[4]  = {u.x, u.y, u.z, u.w};
        float xc[4]  = {x.x, x.y, x.z, x.w};
        float tc[4]  = {ta.x, ta.y, ta.z, ta.w};
        float uuc[4] = {uu.x, uu.y, uu.z, uu.w};
        float xxc[4] = {xx.x, xx.y, xx.z, xx.w};
        float tbc[4] = {tb.x, tb.y, tb.z, tb.w};
#pragma unroll
        for (int j = 0; j < 4; ++j) {
            float resid = fmaf(-ab1, xc[j], uc[j]);
            float rem = fmaxf(Tm1f - tc[j], 0.0f);
            s2a = fmaf(resid, resid, s2a);
            r1a = fmaf(rem, resid, r1a);
            r2a = fmaf(rem * rem, resid, r2a);
            float rs = fmaf(-ab2, xxc[j], uuc[j]);
            float rm = fmaxf(Tm2f - tbc[j], 0.0f);
            s2b = fmaf(rs, rs, s2b);
            r1b = fmaf(rm, rs, r1b);
            r2b = fmaf(rm * rm, rs, r2b);
        }
    }
    // 64-lane wave reduce
#pragma unroll
    for (int o = 32; o >= 1; o >>= 1) {
        s2a += __shfl_xor(s2a, o); r1a += __shfl_xor(r1a, o); r2a += __shfl_xor(r2a, o);
        s2b += __shfl_xor(s2b, o); r1b += __shfl_xor(r1b, o); r2b += __shfl_xor(r2b, o);
    }
    __shared__ float red[TPB / 64][6];
    int wave = tid >> 6, lane = tid & 63;
    if (lane == 0) {
        red[wave][0] = s2a; red[wave][1] = r1a; red[wave][2] = r2a;
        red[wave][3] = s2b; red[wave][4] = r1b; red[wave][5] = r2b;
    }
    __syncthreads();
    if (tid == 0) {
        double S2a = 0, R1a = 0, R2a = 0, S2b = 0, R1b = 0, R2b = 0;
        for (int w = 0; w < TPB / 64; ++w) {
            S2a += (double)red[w][0]; R1a += (double)red[w][1]; R2a += (double)red[w][2];
            S2b += (double)red[w][3]; R1b += (double)red[w][4]; R2b += (double)red[w][5];
        }
        double dtb1 = (double)t[off + 1] - (double)t[off];
        double dtb2 = (double)t_SM[off + 1] - (double)t[off];  // dt_SM = t_SM[:,1]-t[:,0]
        double z0 = (double)z[b * 3 + 0], z1 = (double)z[b * 3 + 1], z2 = (double)z[b * 3 + 2];
        double w0 = (double)z_SM[b * 3 + 0], w1 = (double)z_SM[b * 3 + 1], w2 = (double)z_SM[b * 3 + 2];
        double c1 = epilogue(ws, NT, S2a, R1a, R2a, z0, z1, z2, dtb1);
        double c2 = epilogue(ws + 32, NT, S2b, R1b, R2b, w0, w1, w2, dtb2);
        contrib[b] = c1 + c2;
    }
}

__global__ __launch_bounds__(TPB) void finalize_kernel(
    const double* __restrict__ contrib, int B, float* __restrict__ out)
{
    __shared__ double buf[TPB];
    double s = 0.0;
    for (int i = threadIdx.x; i < B; i += TPB) s += contrib[i];
    buf[threadIdx.x] = s;
    __syncthreads();
    for (int o = TPB / 2; o > 0; o >>= 1) {
        if (threadIdx.x < o) buf[threadIdx.x] += buf[threadIdx.x + o];
        __syncthreads();
    }
    if (threadIdx.x == 0) out[0] = (float)buf[0];
}

extern "C" void kernel_launch(void* const* d_in, const int* in_sizes, int n_in,
                              void* d_out, int out_size, void* d_ws, size_t ws_size,
                              hipStream_t stream) {
    const float* u_t       = (const float*)d_in[0];
    const float* x_t       = (const float*)d_in[1];
    const float* z         = (const float*)d_in[2];
    const float* t         = (const float*)d_in[3];
    const float* t_wait    = (const float*)d_in[4];
    const float* u_t_SM    = (const float*)d_in[5];
    const float* x_t_SM    = (const float*)d_in[6];
    const float* z_SM      = (const float*)d_in[7];
    const float* t_SM      = (const float*)d_in[8];
    const float* t_wait_SM = (const float*)d_in[9];
    const float* hsig_f = (const float*)d_in[10];
    const float* hsig_w = (const float*)d_in[11];
    const float* hxi_f  = (const float*)d_in[12];
    const float* hxi_w  = (const float*)d_in[13];
    const float* hxi_v  = (const float*)d_in[14];
    const float* delta0 = (const float*)d_in[15];
    const float* halpha = (const float*)d_in[16];
    const float* hg     = (const float*)d_in[17];
    const float* hW_aa  = (const float*)d_in[18];
    const float* hsig_a = (const float*)d_in[19];

    int B  = in_sizes[4];          // t_wait length
    int NT = in_sizes[0] / B;      // u_t is B x NT

    double* ws      = (double*)d_ws;
    double* contrib = ws + 64;

    precompute_kernel<<<1, TPB, 0, stream>>>(t, t_wait, t_SM, t_wait_SM,
        hsig_f, hsig_w, hxi_f, hxi_w, hxi_v, delta0, halpha, hg, hW_aa, hsig_a,
        B, NT, ws);
    batch_kernel<<<B, TPB, 0, stream>>>(u_t, x_t, z, t, u_t_SM, x_t_SM, z_SM, t_SM,
        NT, ws, contrib);
    finalize_kernel<<<1, TPB, 0, stream>>>(contrib, B, (float*)d_out);
}

// Round 2
// 240.895 us; speedup vs baseline: 1.0545x; 1.0545x over previous
//
#include <hip/hip_runtime.h>
#include <math.h>

#ifndef M_PI
#define M_PI 3.14159265358979323846
#endif

#define TPB 256

// ---------------------------------------------------------------------------
// Workspace layout:
//   ws[0..31]   (double) : scalars for L1
//   ws[32..63]  (double) : scalars for L2
//   (float*)(ws+64)      : moments, 6 arrays of length 2*B  (half-row partials)
// Per-L scalar layout:
//   0..5 : Sinv_m upper triangle (00,01,02,11,12,22)
//   6..8 : Sinv_s (00,01,11)
//   9    : det_m        10 : det_s        11 : q
//   12..14 : Gff,Gfv,Gvv
//   15 : alpha_br   16 : kf   17 : kv   18 : Tm
//   19 : W_aa   20 : g2   21 : sig_a^2
// ---------------------------------------------------------------------------

__device__ double block_sum_d(double v, double* buf) {
    int tid = threadIdx.x;
    buf[tid] = v;
    __syncthreads();
    for (int o = TPB / 2; o > 0; o >>= 1) {
        if (tid < o) buf[tid] += buf[tid + o];
        __syncthreads();
    }
    double r = buf[0];
    __syncthreads();
    return r;
}

__global__ __launch_bounds__(TPB) void precompute_kernel(
    const float* __restrict__ t, const float* __restrict__ t_wait,
    const float* __restrict__ t_SM, const float* __restrict__ t_wait_SM,
    const float* __restrict__ hsig_f, const float* __restrict__ hsig_w,
    const float* __restrict__ hxi_f, const float* __restrict__ hxi_w,
    const float* __restrict__ hxi_v, const float* __restrict__ delta0,
    const float* __restrict__ halpha, const float* __restrict__ hg,
    const float* __restrict__ hW_aa, const float* __restrict__ hsig_a,
    int B, int NT, double* __restrict__ ws, float* __restrict__ out)
{
    __shared__ double buf[TPB];
    __shared__ double sh[2];
    int tid = threadIdx.x;

    double s1 = 0.0, s2 = 0.0;
    for (int i = tid; i < B; i += TPB) {
        s1 += (double)t_wait[i];
        s2 += (double)t_wait_SM[i];
    }
    double tw1 = block_sum_d(s1, buf);
    double tw2 = block_sum_d(s2, buf);
    if (tid == 0) { sh[0] = 3.0 - tw1 / (double)B; sh[1] = 3.0 - tw2 / (double)B; }
    __syncthreads();
    double Tm1 = sh[0], Tm2 = sh[1];

    double a2 = 0, a3 = 0, a4 = 0, b2 = 0, b3 = 0, b4 = 0;
    for (int i = tid; i < NT; i += TPB) {
        double r1 = Tm1 - (double)t[i];    r1 = r1 > 0.0 ? r1 : 0.0;
        double r2 = Tm2 - (double)t_SM[i]; r2 = r2 > 0.0 ? r2 : 0.0;
        double r1s = r1 * r1, r2s = r2 * r2;
        a2 += r1s; a3 += r1s * r1; a4 += r1s * r1s;
        b2 += r2s; b3 += r2s * r2; b4 += r2s * r2s;
    }
    a2 = block_sum_d(a2, buf); a3 = block_sum_d(a3, buf); a4 = block_sum_d(a4, buf);
    b2 = block_sum_d(b2, buf); b3 = block_sum_d(b3, buf); b4 = block_sum_d(b4, buf);
    if (tid != 0) return;

    out[0] = 0.0f;   // zero the atomic accumulation target

    double sig_f = exp((double)hsig_f[0]);
    double sig_w = exp((double)hsig_w[0]);
    double xi_f  = exp((double)hxi_f[0]);
    double xi_w  = exp((double)hxi_w[0]);
    double xi_v  = exp((double)hxi_v[0]);
    double d0    = (double)delta0[0];
    double alpha = exp((double)halpha[0]);
    double g     = exp((double)hg[0]);
    double W_aa  = exp((double)hW_aa[0]);
    double sig_a = exp((double)hsig_a[0]);
    double g2 = g * g, sig_a2 = sig_a * sig_a;

    for (int L = 0; L < 2; ++L) {
        double sf, xv, ab, Tm, S2, S3, S4;
        if (L == 0) { sf = sig_f; xv = xi_v; ab = alpha; Tm = Tm1; S2 = a2; S3 = a3; S4 = a4; }
        else {
            sf = sqrt(sig_f * sig_f + sig_w * sig_w);
            xv = sqrt(xi_v * xi_v + xi_w * xi_w);
            ab = alpha * W_aa; Tm = Tm2; S2 = b2; S3 = b3; S4 = b4;
        }
        double xf_ = xi_f / sf, xv_ = xv / sf;
        double t_avg = 0.5, t2_avg = 1.0 / 3.0, C_t = 1.0 / 12.0;
        double ixf2 = 1.0 / (xf_ * xf_), ixv2 = 1.0 / (xv_ * xv_);
        double det_inv = (1.0 + ixf2) * (C_t + ixv2) + t_avg * t_avg * ixf2;

        double pre_m = sf * sf / (det_inv * det_inv);
        double Sff = (C_t + ixv2) * (C_t + ixv2) + C_t * t_avg * t_avg;
        double Sfv = t_avg * (ixf2 * ixv2 - C_t);
        double Svv = (t_avg * ixf2) * (t_avg * ixf2) + C_t * (1.0 + ixf2) * (1.0 + ixf2);
        double m11 = pre_m * Sff, m12 = pre_m * Sfv, m22 = pre_m * Svv;
        double detB = m11 * m22 - m12 * m12;
        double Sm00 = 1.0 / sig_a2;
        double Sm11 = m22 / detB, Sm12 = -m12 / detB, Sm22 = m11 / detB;
        double det_m = sig_a2 * detB;

        double pre_s = sf * sf;
        double Sffs = pre_s / ((1.0 + ixf2) * (1.0 + ixf2));
        double Sfvs = pre_s * (t_avg / (xf_ * xf_ + 1.0)) / det_inv;
        double Svvs = pre_s * ((t_avg * ixf2) * (t_avg * ixf2) + C_t * (1.0 + ixf2) * (1.0 + ixf2)) / (det_inv * det_inv);
        double det_s = Sffs * Svvs - Sfvs * Sfvs;
        double Ss00 = Svvs / det_s, Ss01 = -Sfvs / det_s, Ss11 = Sffs / det_s;

        double log_arg = 1.0 + xv_ * xv_ * (C_t + t2_avg / (1.0 + xf_ * xf_));
        double det_ratio = (1.0 / (sf * sf)) * (C_t + 1.0 / (xv_ * xv_) + t2_avg / (1.0 + xf_ * xf_));
        double tq = (log(log_arg) - 2.0 * d0) / det_ratio;
        double q = sqrt(tq > 0.0 ? tq : 0.0);

        double kf = ab / Tm, kv = ab / (2.0 * Tm * Tm);
        double Gff = kf * kf * S2, Gfv = kf * kv * S3, Gvv = kv * kv * S4;

        double* w = ws + L * 32;
        w[0] = Sm00; w[1] = 0.0; w[2] = 0.0; w[3] = Sm11; w[4] = Sm12; w[5] = Sm22;
        w[6] = Ss00; w[7] = Ss01; w[8] = Ss11;
        w[9] = det_m; w[10] = det_s; w[11] = q;
        w[12] = Gff; w[13] = Gfv; w[14] = Gvv;
        w[15] = ab; w[16] = kf; w[17] = kv; w[18] = Tm;
        w[19] = W_aa; w[20] = g2; w[21] = sig_a2;
    }
}

// Pure streaming: one wave per HALF row. 2048 blocks x 256 threads = 8192 waves.
__global__ __launch_bounds__(TPB) void stream_kernel(
    const float* __restrict__ u_t, const float* __restrict__ x_t,
    const float* __restrict__ u_SM, const float* __restrict__ x_SM,
    const float* __restrict__ t, const float* __restrict__ t_SM,
    int NT, int B, const double* __restrict__ ws, float* __restrict__ mom)
{
    int wid  = blockIdx.x * (TPB / 64) + (threadIdx.x >> 6);
    int lane = threadIdx.x & 63;
    int row  = wid >> 1, half = wid & 1;
    int n4 = NT >> 2, h4 = n4 >> 1;

    float ab1 = (float)ws[15],      Tm1 = (float)ws[18];
    float ab2 = (float)ws[32 + 15], Tm2 = (float)ws[32 + 18];

    size_t off = (size_t)row * (size_t)NT;
    const float4* U1 = (const float4*)(u_t + off);
    const float4* X1 = (const float4*)(x_t + off);
    const float4* U2 = (const float4*)(u_SM + off);
    const float4* X2 = (const float4*)(x_SM + off);
    const float4* T1 = (const float4*)t;      // row 0 (tau)
    const float4* T2 = (const float4*)t_SM;

    float s2a = 0, r1a = 0, r2a = 0, s2b = 0, r1b = 0, r2b = 0;
    int iend = (half + 1) * h4;
    for (int i = half * h4 + lane; i < iend; i += 64) {
        float4 u = U1[i], x = X1[i], ta = T1[i];
        float4 uu = U2[i], xx = X2[i], tb = T2[i];
        float uc[4]  = {u.x, u.y, u.z, u.w};
        float xc[4]  = {x.x, x.y, x.z, x.w};
        float tc[4]  = {ta.x, ta.y, ta.z, ta.w};
        float uuc[4] = {uu.x, uu.y, uu.z, uu.w};
        float xxc[4] = {xx.x, xx.y, xx.z, xx.w};
        float tbc[4] = {tb.x, tb.y, tb.z, tb.w};
#pragma unroll
        for (int j = 0; j < 4; ++j) {
            float resid = fmaf(-ab1, xc[j], uc[j]);
            float rem = fmaxf(Tm1 - tc[j], 0.0f);
            s2a = fmaf(resid, resid, s2a);
            r1a = fmaf(rem, resid, r1a);
            r2a = fmaf(rem * rem, resid, r2a);
            float rs = fmaf(-ab2, xxc[j], uuc[j]);
            float rm = fmaxf(Tm2 - tbc[j], 0.0f);
            s2b = fmaf(rs, rs, s2b);
            r1b = fmaf(rm, rs, r1b);
            r2b = fmaf(rm * rm, rs, r2b);
        }
    }
#pragma unroll
    for (int o = 32; o >= 1; o >>= 1) {
        s2a += __shfl_xor(s2a, o); r1a += __shfl_xor(r1a, o); r2a += __shfl_xor(r2a, o);
        s2b += __shfl_xor(s2b, o); r1b += __shfl_xor(r1b, o); r2b += __shfl_xor(r2b, o);
    }
    if (lane == 0) {
        int W = 2 * B;
        mom[0 * W + wid] = s2a; mom[1 * W + wid] = r1a; mom[2 * W + wid] = r2a;
        mom[3 * W + wid] = s2b; mom[4 * W + wid] = r1b; mom[5 * W + wid] = r2b;
    }
}

// Per-batch scalar epilogue (both branches of _get_L + combine), double precision.
__device__ double epilogue(const double* __restrict__ S, int NT,
                           double s2, double R1, double R2,
                           double z0, double z1, double z2, double dtb)
{
    double Sm00 = S[0], Sm01 = S[1], Sm02 = S[2], Sm11 = S[3], Sm12 = S[4], Sm22 = S[5];
    double Ss00 = S[6], Ss01 = S[7], Ss11 = S[8];
    double det_m = S[9], det_s = S[10], q = S[11];
    double Gff = S[12], Gfv = S[13], Gvv = S[14];
    double ab = S[15], kf = S[16], kv = S[17];
    double W_aa = S[19], g2 = S[20], sig_a2 = S[21];

    double cb = dtb / g2;
    double df = kf * R1, dv = kv * R2;
    double data_quad = 0.5 * cb * s2;

    // ---- move branch ----
    double Svo0 = Sm02, Svo1 = Sm12, Svv = Sm22;
    double A00 = Sm00 + cb * Gff, A01 = Sm01 + cb * Gfv, A11 = Sm11 + cb * Gvv;
    double detA = A00 * A11 - A01 * A01;
    double i00 = A11 / detA, i01 = -A01 / detA, i11 = A00 / detA;
    double Woz0 = W_aa * z0, Woz1 = z1, Wvz = ab * z2;
    double Jr0 = Woz0 * Sm00 + Woz1 * Sm01 + Wvz * Svo0 + cb * df;
    double Jr1 = Woz0 * Sm01 + Woz1 * Sm11 + Wvz * Svo1 + cb * dv;
    double Jv0 = Svo0 + cb * Gff, Jv1 = Svo1 + cb * Gfv;
    double AiJv0 = i00 * Jv0 + i01 * Jv1, AiJv1 = i01 * Jv0 + i11 * Jv1;
    double AiJr0 = i00 * Jr0 + i01 * Jr1, AiJr1 = i01 * Jr0 + i11 * Jr1;
    double Jm = Svv * Wvz + Woz0 * Svo0 + Woz1 * Svo1 + cb * df
              - (Jr0 * AiJv0 + Jr1 * AiJv1);
    double km = Svv + cb * Gff - (Jv0 * AiJv0 + Jv1 * AiJv1);
    double y0 = W_aa * z0, y1 = z1, y2 = ab * z2;
    double zq = y0 * y0 * Sm00 + y1 * y1 * Sm11 + y2 * y2 * Sm22
              + 2.0 * (y0 * y1 * Sm01 + y0 * y2 * Sm02 + y1 * y2 * Sm12);
    double Zm = 0.5 * zq + data_quad - 0.5 * (Jr0 * AiJr0 + Jr1 * AiJr1) - 0.5 * Jm * Jm / km;

    // ---- stat branch ----
    double As = Ss00 + cb * Gff;
    double Wozs = z1, Wvzs = ab * z2;
    double Jrs = Wozs * Ss00 + Wvzs * Ss01 + cb * df;
    double Jvs = Ss01;
    double Js = Ss11 * Wvzs + Wozs * Ss01 - Jrs * Jvs / As;
    double ks = Ss11 - Jvs * Jvs / As;
    double ys1 = ab * z2;
    double zqs = z1 * z1 * Ss00 + 2.0 * z1 * ys1 * Ss01 + ys1 * ys1 * Ss11;
    double Zs = 0.5 * zqs + data_quad - 0.5 * Jrs * Jrs / As - 0.5 * Js * Js / ks;

    // ---- combine ----
    double pre_m = km * detA * det_m * sig_a2;
    double pre_s = ks * As * det_s;
    double sm = sqrt(2.0 * km), ss = sqrt(2.0 * ks);
    double em = 1.0 + 0.5 * erf((Jm - km * q) / sm) - 0.5 * erf((Jm + km * q) / sm);
    double es = 0.5 * erf((Js + ks * q) / ss) - 0.5 * erf((Js - ks * q) / ss);
    double Lm = exp(-Zm) * em / sqrt(pre_m);
    double Ls = exp(-Zs) * es / sqrt(pre_s);
    return (double)NT * log(2.0 * M_PI * g2 / dtb) - log(Lm + Ls);
}

// One THREAD per batch row: all lanes busy on the double epilogue.
__global__ __launch_bounds__(TPB) void epilogue_kernel(
    const float* __restrict__ z, const float* __restrict__ z_SM,
    const float* __restrict__ t, const float* __restrict__ t_SM,
    int NT, int B, const double* __restrict__ ws,
    const float* __restrict__ mom, float* __restrict__ out)
{
    int row = blockIdx.x * TPB + threadIdx.x;
    double c = 0.0;
    if (row < B) {
        int W = 2 * B;
        double S2a = (double)mom[0 * W + 2 * row] + (double)mom[0 * W + 2 * row + 1];
        double R1a = (double)mom[1 * W + 2 * row] + (double)mom[1 * W + 2 * row + 1];
        double R2a = (double)mom[2 * W + 2 * row] + (double)mom[2 * W + 2 * row + 1];
        double S2b = (double)mom[3 * W + 2 * row] + (double)mom[3 * W + 2 * row + 1];
        double R1b = (double)mom[4 * W + 2 * row] + (double)mom[4 * W + 2 * row + 1];
        double R2b = (double)mom[5 * W + 2 * row] + (double)mom[5 * W + 2 * row + 1];
        size_t off = (size_t)row * (size_t)NT;
        double dtb1 = (double)t[off + 1] - (double)t[off];
        double dtb2 = (double)t_SM[off + 1] - (double)t[off];
        double z0 = (double)z[row * 3 + 0], z1 = (double)z[row * 3 + 1], z2 = (double)z[row * 3 + 2];
        double w0 = (double)z_SM[row * 3 + 0], w1 = (double)z_SM[row * 3 + 1], w2 = (double)z_SM[row * 3 + 2];
        c = epilogue(ws, NT, S2a, R1a, R2a, z0, z1, z2, dtb1)
          + epilogue(ws + 32, NT, S2b, R1b, R2b, w0, w1, w2, dtb2);
    }
    __shared__ double buf[TPB];
    int tid = threadIdx.x;
    buf[tid] = c;
    __syncthreads();
    for (int o = TPB / 2; o > 0; o >>= 1) {
        if (tid < o) buf[tid] += buf[tid + o];
        __syncthreads();
    }
    if (tid == 0) atomicAdd(out, (float)buf[0]);
}

extern "C" void kernel_launch(void* const* d_in, const int* in_sizes, int n_in,
                              void* d_out, int out_size, void* d_ws, size_t ws_size,
                              hipStream_t stream) {
    const float* u_t       = (const float*)d_in[0];
    const float* x_t       = (const float*)d_in[1];
    const float* z         = (const float*)d_in[2];
    const float* t         = (const float*)d_in[3];
    const float* t_wait    = (const float*)d_in[4];
    const float* u_t_SM    = (const float*)d_in[5];
    const float* x_t_SM    = (const float*)d_in[6];
    const float* z_SM      = (const float*)d_in[7];
    const float* t_SM      = (const float*)d_in[8];
    const float* t_wait_SM = (const float*)d_in[9];
    const float* hsig_f = (const float*)d_in[10];
    const float* hsig_w = (const float*)d_in[11];
    const float* hxi_f  = (const float*)d_in[12];
    const float* hxi_w  = (const float*)d_in[13];
    const float* hxi_v  = (const float*)d_in[14];
    const float* delta0 = (const float*)d_in[15];
    const float* halpha = (const float*)d_in[16];
    const float* hg     = (const float*)d_in[17];
    const float* hW_aa  = (const float*)d_in[18];
    const float* hsig_a = (const float*)d_in[19];

    int B  = in_sizes[4];
    int NT = in_sizes[0] / B;

    double* ws  = (double*)d_ws;
    float*  mom = (float*)(ws + 64);
    float*  out = (float*)d_out;

    precompute_kernel<<<1, TPB, 0, stream>>>(t, t_wait, t_SM, t_wait_SM,
        hsig_f, hsig_w, hxi_f, hxi_w, hxi_v, delta0, halpha, hg, hW_aa, hsig_a,
        B, NT, ws, out);

    int nwaves = 2 * B;                 // one wave per half-row
    int nblocks = nwaves / (TPB / 64);  // 4 waves per block
    stream_kernel<<<nblocks, TPB, 0, stream>>>(u_t, x_t, u_t_SM, x_t_SM, t, t_SM,
        NT, B, ws, mom);

    epilogue_kernel<<<(B + TPB - 1) / TPB, TPB, 0, stream>>>(z, z_SM, t, t_SM,
        NT, B, ws, mom, out);
}